// Round 1
// baseline (25.688 us; speedup 1.0000x reference)
//
#include <hip/hip_runtime.h>

namespace {
constexpr int R = 16;
constexpr int A = 4;

// d_ws float layout (all offsets in floats)
constexpr int OFF_C1O = 0;    // c1 original order      [16]
constexpr int OFF_C2O = 16;   // c2 original order      [16]
constexpr int OFF_C1S = 32;   // c1 sorted ascending    [16]
constexpr int OFF_C2S = 48;   // c2 sorted ascending    [16]
constexpr int OFF_ML  = 64;   // mean, idx1-permuted    [64]  (k*4+a)
constexpr int OFF_KUL = 128;  // -0.5/s_hi^2, idx1-perm [64]
constexpr int OFF_KLL = 192;  // -0.5/s_lo^2, idx1-perm [64]
constexpr int OFF_MR  = 256;  // mean, idx2-permuted    [64]
constexpr int OFF_KUR = 320;  // -0.5/s_hi^2, idx2-perm [64]
constexpr int OFF_KLR = 384;  // -0.5/s_lo^2, idx2-perm [64]
}

// One tiny block: sort c1/c2 (stable, rank-count), emit pre-permuted
// Gaussian coefficients so the main kernel needs no sorting, no shared
// memory, and no runtime-indexed register arrays.
__global__ __launch_bounds__(128) void t2fls_prep(
    const float* __restrict__ frb,
    const float* __restrict__ c1g,
    const float* __restrict__ c2g,
    float* __restrict__ ws)
{
    __shared__ float c1o[R], c2o[R];
    __shared__ int idx1[R], idx2[R];
    const int t = threadIdx.x;
    if (t < R) { c1o[t] = c1g[t]; c2o[t] = c2g[t]; }
    __syncthreads();
    if (t < 2 * R) {
        const bool second = (t >= R);
        const float* c = second ? c2o : c1o;
        const int i = t & (R - 1);
        const float ci = c[i];
        int rank = 0;
        for (int j = 0; j < R; ++j) {
            const float cj = c[j];
            rank += (cj < ci) || (cj == ci && j < i);   // stable argsort
        }
        if (!second) { idx1[rank] = i; ws[OFF_C1S + rank] = ci; ws[OFF_C1O + i] = ci; }
        else         { idx2[rank] = i; ws[OFF_C2S + rank] = ci; ws[OFF_C2O + i] = ci; }
    }
    __syncthreads();
    if (t < 2 * R * A) {
        const bool second = (t >= R * A);
        const int u = second ? (t - R * A) : t;
        const int k = u >> 2, a = u & 3;
        const int i = second ? idx2[k] : idx1[k];
        const float m  = frb[(i * A + a) * 3 + 0];
        const float s1 = frb[(i * A + a) * 3 + 1];
        const float s2 = frb[(i * A + a) * 3 + 2];
        const float slo = fminf(s1, s2), shi = fmaxf(s1, s2);
        const float ku = -0.5f / (shi * shi);
        const float kl = -0.5f / (slo * slo);
        if (!second) { ws[OFF_ML + u] = m; ws[OFF_KUL + u] = ku; ws[OFF_KLL + u] = kl; }
        else         { ws[OFF_MR + u] = m; ws[OFF_KUR + u] = ku; ws[OFF_KLR + u] = kl; }
    }
}

// One thread per sample. All P[...] indices are compile-time constants off a
// uniform pointer -> scalar s_load (constant cache), keeping the VALU free
// for the exp/KM arithmetic. All register arrays statically indexed.
__global__ __launch_bounds__(256) void t2fls_main(
    const float* __restrict__ x,
    const float* __restrict__ P,
    float* __restrict__ out,
    int n)
{
    const int gid = blockIdx.x * blockDim.x + threadIdx.x;
    if (gid >= n) return;

    const float4 xv = reinterpret_cast<const float4*>(x)[gid];
    const float xx[4] = {xv.x, xv.y, xv.z, xv.w};

    const float BIG = 3.402823466e38f;

    // ---------------- left endpoint (c1-sorted space) ----------------
    float left;
    {
        float UUs[R], LLs[R];
        float s0 = 0.f, t0 = 0.f;
        #pragma unroll
        for (int k = 0; k < R; ++k) {
            float eU = 0.f, eL = 0.f;
            #pragma unroll
            for (int a = 0; a < A; ++a) {
                const float z = xx[a] - P[OFF_ML + k * 4 + a];
                const float z2 = z * z;
                eU = fmaf(P[OFF_KUL + k * 4 + a], z2, eU);
                eL = fmaf(P[OFF_KLL + k * 4 + a], z2, eL);
            }
            const float uu = expf(eU);   // prod_a mu_hi == exp(sum)
            const float ll = expf(eL);
            UUs[k] = uu; LLs[k] = ll;
            s0 += P[OFF_C1S + k] * ll;
            t0 += ll;
        }
        const float q0 = s0 / t0;
        float ss = s0, tt = t0;
        float runmin = BIG, best = BIG;
        int loc = 0;
        #pragma unroll
        for (int k = 0; k < R; ++k) {
            const float d = UUs[k] - LLs[k];
            ss += P[OFF_C1S + k] * d;        // inclusive cumsum
            tt += d;
            const float ratio = ss / tt;     // IEEE divide (matches numpy)
            runmin = fminf(runmin, ratio);
            const float lout = fminf(runmin, q0);
            if (lout < best) { best = lout; loc = k; }   // first-occurrence argmin
        }
        float num = 0.f, den = 0.f;
        #pragma unroll
        for (int k = 0; k < R; ++k) {
            const float v = (k <= loc) ? UUs[k] : LLs[k];
            num += P[OFF_C1O + k] * v;   // NOTE: reference pairs UNSORTED c1 with sorted-space L_U
            den += v;
        }
        left = num / den;
    }

    // ---------------- right endpoint (c2-sorted space) ----------------
    float right;
    {
        float UUr[R], LLr[R];
        float s0 = 0.f, t0 = 0.f;
        #pragma unroll
        for (int k = 0; k < R; ++k) {
            float eU = 0.f, eL = 0.f;
            #pragma unroll
            for (int a = 0; a < A; ++a) {
                const float z = xx[a] - P[OFF_MR + k * 4 + a];
                const float z2 = z * z;
                eU = fmaf(P[OFF_KUR + k * 4 + a], z2, eU);
                eL = fmaf(P[OFF_KLR + k * 4 + a], z2, eL);
            }
            const float uu = expf(eU);
            const float ll = expf(eL);
            UUr[k] = uu; LLr[k] = ll;
            s0 += P[OFF_C2S + k] * uu;
            t0 += uu;
        }
        const float q0 = s0 / t0;
        float ss = s0, tt = t0;
        float runmax = -BIG, best = -BIG;
        int loc = 0;
        #pragma unroll
        for (int k = 0; k < R; ++k) {
            const float d = LLr[k] - UUr[k];
            ss += P[OFF_C2S + k] * d;
            tt += d;
            const float ratio = ss / tt;
            runmax = fmaxf(runmax, ratio);
            const float rout = fmaxf(runmax, q0);
            if (rout > best) { best = rout; loc = k; }   // first-occurrence argmax
        }
        float num = 0.f, den = 0.f;
        #pragma unroll
        for (int k = 0; k < R; ++k) {
            const float v = (k <= loc) ? LLr[k] : UUr[k];
            num += P[OFF_C2O + k] * v;   // unsorted c2, sorted-space R_L
            den += v;
        }
        right = num / den;
    }

    out[gid] = 0.5f * (left + right);
}

extern "C" void kernel_launch(void* const* d_in, const int* in_sizes, int n_in,
                              void* d_out, int out_size, void* d_ws, size_t ws_size,
                              hipStream_t stream) {
    const float* x   = (const float*)d_in[0];   // (N, 4) float32
    const float* frb = (const float*)d_in[1];   // (R*A*3,) float32
    const float* c1  = (const float*)d_in[2];   // (R,) float32
    const float* c2  = (const float*)d_in[3];   // (R,) float32
    float* out = (float*)d_out;                 // (N,) float32
    float* ws  = (float*)d_ws;                  // needs 448 floats = 1792 B

    const int n = out_size;                     // N = 262144
    hipLaunchKernelGGL(t2fls_prep, dim3(1), dim3(128), 0, stream, frb, c1, c2, ws);
    const int blocks = (n + 255) / 256;
    hipLaunchKernelGGL(t2fls_main, dim3(blocks), dim3(256), 0, stream, x, ws, out, n);
}

// Round 2
// 19.047 us; speedup vs baseline: 1.3487x; 1.3487x over previous
//
#include <hip/hip_runtime.h>

namespace {
constexpr int R = 16;
constexpr int A = 4;

// d_ws float layout (all offsets in floats)
constexpr int OFF_C1O = 0;    // c1 original order      [16]
constexpr int OFF_C2O = 16;   // c2 original order      [16]
constexpr int OFF_C1S = 32;   // c1 sorted ascending    [16]
constexpr int OFF_C2S = 48;   // c2 sorted ascending    [16]
constexpr int OFF_ML  = 64;   // mean, idx1-permuted    [64]  (k*4+a)
constexpr int OFF_KUL = 128;  // -0.5*log2e/s_hi^2, idx1 [64]
constexpr int OFF_KLL = 192;  // -0.5*log2e/s_lo^2, idx1 [64]
constexpr int OFF_MR  = 256;  // mean, idx2-permuted    [64]
constexpr int OFF_KUR = 320;  // -0.5*log2e/s_hi^2, idx2 [64]
constexpr int OFF_KLR = 384;  // -0.5*log2e/s_lo^2, idx2 [64]
}

// One tiny block: stable argsort of c1/c2, emit pre-permuted Gaussian
// coefficients with log2e folded in so the main kernel's membership is a
// pure fma chain + one v_exp_f32 (exp2).
__global__ __launch_bounds__(128) void t2fls_prep(
    const float* __restrict__ frb,
    const float* __restrict__ c1g,
    const float* __restrict__ c2g,
    float* __restrict__ ws)
{
    __shared__ float c1o[R], c2o[R];
    __shared__ int idx1[R], idx2[R];
    const int t = threadIdx.x;
    if (t < R) { c1o[t] = c1g[t]; c2o[t] = c2g[t]; }
    __syncthreads();
    if (t < 2 * R) {
        const bool second = (t >= R);
        const float* c = second ? c2o : c1o;
        const int i = t & (R - 1);
        const float ci = c[i];
        int rank = 0;
        for (int j = 0; j < R; ++j) {
            const float cj = c[j];
            rank += (cj < ci) || (cj == ci && j < i);   // stable argsort
        }
        if (!second) { idx1[rank] = i; ws[OFF_C1S + rank] = ci; ws[OFF_C1O + i] = ci; }
        else         { idx2[rank] = i; ws[OFF_C2S + rank] = ci; ws[OFF_C2O + i] = ci; }
    }
    __syncthreads();
    if (t < 2 * R * A) {
        const bool second = (t >= R * A);
        const int u = second ? (t - R * A) : t;
        const int k = u >> 2, a = u & 3;
        const int i = second ? idx2[k] : idx1[k];
        const float m  = frb[(i * A + a) * 3 + 0];
        const float s1 = frb[(i * A + a) * 3 + 1];
        const float s2 = frb[(i * A + a) * 3 + 2];
        const float slo = fminf(s1, s2), shi = fmaxf(s1, s2);
        const float HALF_LOG2E = 0.7213475204444817f;   // 0.5*log2(e)
        const float ku = -HALF_LOG2E / (shi * shi);
        const float kl = -HALF_LOG2E / (slo * slo);
        if (!second) { ws[OFF_ML + u] = m; ws[OFF_KUL + u] = ku; ws[OFF_KLL + u] = kl; }
        else         { ws[OFF_MR + u] = m; ws[OFF_KUR + u] = ku; ws[OFF_KLR + u] = kl; }
    }
}

// One thread per sample. Param reads are compile-time-constant offsets off a
// uniform pointer -> scalar s_load / constant cache. No divides except the
// final two; no libm expf (exp2 builtin, log2e pre-folded); KM endpoint via
// cross-multiplied comparisons with num/den latched at the argmin update.
__global__ __launch_bounds__(256) void t2fls_main(
    const float* __restrict__ x,
    const float* __restrict__ P,
    float* __restrict__ out,
    int n)
{
    const int gid = blockIdx.x * blockDim.x + threadIdx.x;
    if (gid >= n) return;

    const float4 xv = reinterpret_cast<const float4*>(x)[gid];
    const float xx[4] = {xv.x, xv.y, xv.z, xv.w};

    // ---------------- left endpoint (c1-sorted space) ----------------
    float left;
    {
        float d[R];
        float s0 = 0.f, t0 = 0.f, su = 0.f;   // su = sum c1_orig * LL_sorted
        #pragma unroll
        for (int k = 0; k < R; ++k) {
            float eU = 0.f, eL = 0.f;
            #pragma unroll
            for (int a = 0; a < A; ++a) {
                const float z = xx[a] - P[OFF_ML + k * 4 + a];
                const float z2 = z * z;
                eU = fmaf(P[OFF_KUL + k * 4 + a], z2, eU);
                eL = fmaf(P[OFF_KLL + k * 4 + a], z2, eL);
            }
            const float uu = __builtin_amdgcn_exp2f(eU);  // prod_a mu_hi
            const float ll = __builtin_amdgcn_exp2f(eL);
            s0 = fmaf(P[OFF_C1S + k], ll, s0);
            t0 += ll;
            su = fmaf(P[OFF_C1O + k], ll, su);
            d[k] = uu - ll;                               // d >= 0
        }
        // k = 0 (inclusive cumsum starts here)
        float ss = fmaf(P[OFF_C1S + 0], d[0], s0);
        float tt = t0 + d[0];
        float cn = P[OFF_C1O + 0] * d[0];
        float sb = ss, tb = tt, cnb = cn;
        const float tt0 = tt, cn0 = cn;
        #pragma unroll
        for (int k = 1; k < R; ++k) {
            ss = fmaf(P[OFF_C1S + k], d[k], ss);
            tt += d[k];
            cn = fmaf(P[OFF_C1O + k], d[k], cn);
            // ratio_k < best  <=>  ss/tt < sb/tb  <=>  ss*tb < sb*tt  (tt,tb > 0)
            const bool lt = (ss * tb) < (sb * tt);
            if (lt) { sb = ss; tb = tt; cnb = cn; }       // first-occurrence argmin
        }
        // L_out = min(cummin(ratio), q0): argmin is 0 iff q0 <= min_ratio
        // q0 <= sb/tb  <=>  s0*tb <= sb*t0
        if ((s0 * tb) <= (sb * t0)) { tb = tt0; cnb = cn0; }
        left = (su + cnb) / tb;                           // den = t0+sum(d,k<=loc) = tb
    }

    // ---------------- right endpoint (c2-sorted space) ----------------
    float right;
    {
        float d[R];
        float s0 = 0.f, t0 = 0.f, su = 0.f;   // su = sum c2_orig * UU_sorted
        #pragma unroll
        for (int k = 0; k < R; ++k) {
            float eU = 0.f, eL = 0.f;
            #pragma unroll
            for (int a = 0; a < A; ++a) {
                const float z = xx[a] - P[OFF_MR + k * 4 + a];
                const float z2 = z * z;
                eU = fmaf(P[OFF_KUR + k * 4 + a], z2, eU);
                eL = fmaf(P[OFF_KLR + k * 4 + a], z2, eL);
            }
            const float uu = __builtin_amdgcn_exp2f(eU);
            const float ll = __builtin_amdgcn_exp2f(eL);
            s0 = fmaf(P[OFF_C2S + k], uu, s0);
            t0 += uu;
            su = fmaf(P[OFF_C2O + k], uu, su);
            d[k] = ll - uu;                               // d <= 0
        }
        float ss = fmaf(P[OFF_C2S + 0], d[0], s0);
        float tt = t0 + d[0];
        float cn = P[OFF_C2O + 0] * d[0];
        float sb = ss, tb = tt, cnb = cn;
        const float tt0 = tt, cn0 = cn;
        #pragma unroll
        for (int k = 1; k < R; ++k) {
            ss = fmaf(P[OFF_C2S + k], d[k], ss);
            tt += d[k];
            cn = fmaf(P[OFF_C2O + k], d[k], cn);
            // ratio_k > best  <=>  ss*tb > sb*tt  (tt,tb > 0)
            const bool gt = (ss * tb) > (sb * tt);
            if (gt) { sb = ss; tb = tt; cnb = cn; }       // first-occurrence argmax
        }
        // R_out = max(cummax(ratio), q0): argmax is 0 iff q0 >= max_ratio
        if ((s0 * tb) >= (sb * t0)) { tb = tt0; cnb = cn0; }
        right = (su + cnb) / tb;
    }

    out[gid] = 0.5f * (left + right);
}

extern "C" void kernel_launch(void* const* d_in, const int* in_sizes, int n_in,
                              void* d_out, int out_size, void* d_ws, size_t ws_size,
                              hipStream_t stream) {
    const float* x   = (const float*)d_in[0];   // (N, 4) float32
    const float* frb = (const float*)d_in[1];   // (R*A*3,) float32
    const float* c1  = (const float*)d_in[2];   // (R,) float32
    const float* c2  = (const float*)d_in[3];   // (R,) float32
    float* out = (float*)d_out;                 // (N,) float32
    float* ws  = (float*)d_ws;                  // needs 448 floats = 1792 B

    const int n = out_size;                     // N = 262144
    hipLaunchKernelGGL(t2fls_prep, dim3(1), dim3(128), 0, stream, frb, c1, c2, ws);
    const int blocks = (n + 255) / 256;
    hipLaunchKernelGGL(t2fls_main, dim3(blocks), dim3(256), 0, stream, x, ws, out, n);
}